// Round 1
// baseline (532.088 us; speedup 1.0000x reference)
//
#include <hip/hip_runtime.h>
#include <math.h>

namespace {

constexpr int Bsz = 8192;
constexpr int Fsz = 256;

constexpr int BT = 32;            // b tile
constexpr int NT = 32;            // n tile
constexpr int MT = 16;            // k (m) tile
constexpr int RS = 12;            // LDS row stride (words) per b/n row (8 payload + 4 pad)
constexpr int MS = BT * RS + 4;   // LDS m stride = 388 words (mod 32 == 4 -> rotates banks)

// ---- compile-time Clifford algebra tables (Cl(3,0), CEGNN blade order) ----
struct Tables {
  int   jidx[64];   // output blade for pair (i,k): j = idx[mask_i ^ mask_k]
  float sgn[64];    // reordering sign
  int   path[64];   // index into w_gp's 20 paths: (grade_i, grade_j, grade_k)
  int   gr[8];      // grade of blade
};

constexpr int cpopc(int v) { int c = 0; while (v) { c += v & 1; v >>= 1; } return c; }

constexpr Tables make_tables() {
  Tables t{};
  constexpr int MASKS[8] = {0, 1, 2, 4, 3, 5, 6, 7};
  int inv[8] = {};
  for (int i = 0; i < 8; ++i) inv[MASKS[i]] = i;
  int grade[8] = {};
  for (int i = 0; i < 8; ++i) { grade[i] = cpopc(MASKS[i]); t.gr[i] = grade[i]; }
  int pidx[4][4][4] = {};
  for (int a = 0; a < 4; ++a)
    for (int b = 0; b < 4; ++b)
      for (int c = 0; c < 4; ++c) pidx[a][b][c] = -1;
  int np = 0;
  for (int gi = 0; gi < 4; ++gi)
    for (int gj = 0; gj < 4; ++gj)
      for (int gk = 0; gk < 4; ++gk) {
        bool any = false;
        for (int i = 0; i < 8; ++i)
          for (int k = 0; k < 8; ++k)
            if (grade[i] == gi && grade[k] == gk && cpopc(MASKS[i] ^ MASKS[k]) == gj) any = true;
        if (any) pidx[gi][gj][gk] = np++;
      }
  for (int i = 0; i < 8; ++i)
    for (int k = 0; k < 8; ++k) {
      const int mi = MASKS[i], mk = MASKS[k];
      int s = 0, aa = mi >> 1;
      while (aa) { s += cpopc(aa & mk); aa >>= 1; }
      t.jidx[i * 8 + k] = inv[mi ^ mk];
      t.sgn[i * 8 + k]  = (s & 1) ? -1.0f : 1.0f;
      t.path[i * 8 + k] = pidx[grade[i]][cpopc(mi ^ mk)][grade[k]];
    }
  return t;
}

struct f8 { float v[8]; };

__device__ inline f8 ld8(const float* p) {
  f8 r;
  float4 a = *(const float4*)p;
  float4 b = *(const float4*)(p + 4);
  r.v[0] = a.x; r.v[1] = a.y; r.v[2] = a.z; r.v[3] = a.w;
  r.v[4] = b.x; r.v[5] = b.y; r.v[6] = b.z; r.v[7] = b.w;
  return r;
}

__global__ __launch_bounds__(256) void sgp_fused(
    const float* __restrict__ x,    // [B, F, 8]
    const float* __restrict__ wl,   // [F, F, 4]
    const float* __restrict__ blft, // [1, F, 1]
    const float* __restrict__ wr,   // [F, F, 4]
    const float* __restrict__ an,   // [F, 4]
    const float* __restrict__ wgp,  // [F, 20]
    float* __restrict__ out)        // [B, F, 8]
{
  constexpr Tables T = make_tables();

  __shared__ float xs[MT * MS];   // x tile:  [m][b(32) * RS + blade]
  __shared__ float wsh[MT * MS];  // w tile:  [m][n(32) * RS + (0..3 left | 4..7 right)]

  const int tid = threadIdx.x;
  const int tx = tid & 15;    // n micro index
  const int ty = tid >> 4;    // b micro index
  const int bb = blockIdx.x * BT;
  const int nn = blockIdx.y * NT;

  const int rl = tid >> 4;    // staging row 0..15 (row rl and rl+16)
  const int cm = tid & 15;    // staging m 0..15

  // accumulators: [b half][n half][blade]
  float accL[2][2][8];
  float accR[2][2][8];
  #pragma unroll
  for (int a = 0; a < 2; ++a)
    #pragma unroll
    for (int c = 0; c < 2; ++c)
      #pragma unroll
      for (int i = 0; i < 8; ++i) { accL[a][c][i] = 0.f; accR[a][c][i] = 0.f; }

  for (int mm = 0; mm < Fsz; mm += MT) {
    // ---- stage x tile ----
    {
      const float* g0 = x + (((size_t)(bb + rl)) * Fsz + (mm + cm)) * 8;
      const float* g1 = x + (((size_t)(bb + rl + 16)) * Fsz + (mm + cm)) * 8;
      float4 a0 = ((const float4*)g0)[0];
      float4 a1 = ((const float4*)g0)[1];
      float4 b0 = ((const float4*)g1)[0];
      float4 b1 = ((const float4*)g1)[1];
      *(float4*)&xs[cm * MS + rl * RS + 0] = a0;
      *(float4*)&xs[cm * MS + rl * RS + 4] = a1;
      *(float4*)&xs[cm * MS + (rl + 16) * RS + 0] = b0;
      *(float4*)&xs[cm * MS + (rl + 16) * RS + 4] = b1;
      // ---- stage weight tiles (left into lanes 0..3, right into 4..7) ----
      float4 l0 = *(const float4*)(wl + (((size_t)(nn + rl)) * Fsz + (mm + cm)) * 4);
      float4 l1 = *(const float4*)(wl + (((size_t)(nn + rl + 16)) * Fsz + (mm + cm)) * 4);
      float4 r0 = *(const float4*)(wr + (((size_t)(nn + rl)) * Fsz + (mm + cm)) * 4);
      float4 r1 = *(const float4*)(wr + (((size_t)(nn + rl + 16)) * Fsz + (mm + cm)) * 4);
      *(float4*)&wsh[cm * MS + rl * RS + 0] = l0;
      *(float4*)&wsh[cm * MS + rl * RS + 4] = r0;
      *(float4*)&wsh[cm * MS + (rl + 16) * RS + 0] = l1;
      *(float4*)&wsh[cm * MS + (rl + 16) * RS + 4] = r1;
    }
    __syncthreads();

    #pragma unroll
    for (int m = 0; m < MT; ++m) {
      f8 xf0 = ld8(&xs[m * MS + ty * RS]);
      f8 xf1 = ld8(&xs[m * MS + (ty + 16) * RS]);
      f8 wv0 = ld8(&wsh[m * MS + tx * RS]);        // [0..3]=left g, [4..7]=right g
      f8 wv1 = ld8(&wsh[m * MS + (tx + 16) * RS]);

      #pragma unroll
      for (int i = 0; i < 8; ++i) {
        const int g = T.gr[i];
        accL[0][0][i] += xf0.v[i] * wv0.v[g];
        accR[0][0][i] += xf0.v[i] * wv0.v[4 + g];
        accL[0][1][i] += xf0.v[i] * wv1.v[g];
        accR[0][1][i] += xf0.v[i] * wv1.v[4 + g];
        accL[1][0][i] += xf1.v[i] * wv0.v[g];
        accR[1][0][i] += xf1.v[i] * wv0.v[4 + g];
        accL[1][1][i] += xf1.v[i] * wv1.v[g];
        accR[1][1][i] += xf1.v[i] * wv1.v[4 + g];
      }
    }
    __syncthreads();
  }

  // ---------------- epilogue ----------------
  const float inv_sqrt2 = 0.7071067811865476f;

  #pragma unroll
  for (int c = 0; c < 2; ++c) {
    const int n = nn + tx + c * 16;
    float4 anv = *(const float4*)(an + (size_t)n * 4);
    const float bias = blft[n];
    float wd[20];
    #pragma unroll
    for (int q = 0; q < 5; ++q) {
      float4 w4 = *(const float4*)(wgp + (size_t)n * 20 + q * 4);
      wd[q * 4 + 0] = w4.x; wd[q * 4 + 1] = w4.y;
      wd[q * 4 + 2] = w4.z; wd[q * 4 + 3] = w4.w;
    }
    float sg[4];
    sg[0] = 1.f / (1.f + expf(-anv.x));
    sg[1] = 1.f / (1.f + expf(-anv.y));
    sg[2] = 1.f / (1.f + expf(-anv.z));
    sg[3] = 1.f / (1.f + expf(-anv.w));

    #pragma unroll
    for (int a = 0; a < 2; ++a) {
      const int b = bb + ty + a * 16;
      const float* r = accR[a][c];

      float q0 = r[0] * r[0];
      float q1 = r[1] * r[1] + r[2] * r[2] + r[3] * r[3];
      float q2 = r[4] * r[4] + r[5] * r[5] + r[6] * r[6];
      float q3 = r[7] * r[7];
      float nrm[4];
      nrm[0] = sqrtf(sqrtf(q0 * q0 + 1e-16f));
      nrm[1] = sqrtf(sqrtf(q1 * q1 + 1e-16f));
      nrm[2] = sqrtf(sqrtf(q2 * q2 + 1e-16f));
      nrm[3] = sqrtf(sqrtf(q3 * q3 + 1e-16f));
      float invn[4];
      #pragma unroll
      for (int g = 0; g < 4; ++g)
        invn[g] = 1.0f / (sg[g] * (nrm[g] - 1.0f) + 1.0f + 1e-6f);

      float xr[8];
      #pragma unroll
      for (int i = 0; i < 8; ++i) xr[i] = r[i] * invn[T.gr[i]];

      f8 xv = ld8(x + (((size_t)b) * Fsz + n) * 8);

      float gp[8] = {0, 0, 0, 0, 0, 0, 0, 0};
      #pragma unroll
      for (int i = 0; i < 8; ++i) {
        #pragma unroll
        for (int k = 0; k < 8; ++k) {
          const int p = i * 8 + k;
          gp[T.jidx[p]] += T.sgn[p] * wd[T.path[p]] * xv.v[i] * xr[k];
        }
      }

      float o[8];
      #pragma unroll
      for (int i = 0; i < 8; ++i)
        o[i] = (accL[a][c][i] + gp[i] + (i == 0 ? bias : 0.f)) * inv_sqrt2;

      float4* dst = (float4*)(out + (((size_t)b) * Fsz + n) * 8);
      dst[0] = make_float4(o[0], o[1], o[2], o[3]);
      dst[1] = make_float4(o[4], o[5], o[6], o[7]);
    }
  }
}

}  // namespace

extern "C" void kernel_launch(void* const* d_in, const int* in_sizes, int n_in,
                              void* d_out, int out_size, void* d_ws, size_t ws_size,
                              hipStream_t stream) {
  const float* x   = (const float*)d_in[0];
  const float* wl  = (const float*)d_in[1];
  const float* bl  = (const float*)d_in[2];
  const float* wr  = (const float*)d_in[3];
  const float* an  = (const float*)d_in[4];
  const float* wgp = (const float*)d_in[5];
  float* out = (float*)d_out;

  dim3 grid(Bsz / BT, Fsz / NT);  // (256, 8)
  sgp_fused<<<grid, dim3(256), 0, stream>>>(x, wl, bl, wr, an, wgp, out);
}